// Round 10
// baseline (307.287 us; speedup 1.0000x reference)
//
#include <hip/hip_runtime.h>
#include <math.h>

#define D_IN  128
#define H_DIM 64
#define D_OUT 40
#define BW_SHIFT 9            // bucket width = 512 nodes
#define BW_NODES 512
#define BINA_CHUNK 4096
#define BUCKET_CAP 9216       // fixed bucket capacity; mean 8192, sd ~90 -> +11 sigma

typedef unsigned int uint32;

__device__ __forceinline__ unsigned short f2bf(float v) {
    uint32 b = __float_as_uint(v);
    b += 0x7fffu + ((b >> 16) & 1u);      // RNE
    return (unsigned short)(b >> 16);
}
__device__ __forceinline__ float bf2f(unsigned short u) {
    return __uint_as_float(((uint32)u) << 16);
}

// ============ cursor init: gcursor[b] = b*CAP ============
__global__ void cursor_init_kernel(int* __restrict__ gcursor, int NBUCK) {
    int i = blockIdx.x * 256 + threadIdx.x;
    if (i < NBUCK) gcursor[i] = i * BUCKET_CAP;
}

// ============ Phase A: scatter packed edges into fixed bucket regions ============
__global__ __launch_bounds__(256) void binA_scatter_kernel(const int* __restrict__ src,
                                                           const int* __restrict__ dst,
                                                           int* __restrict__ gcursor,
                                                           uint32* __restrict__ binned,
                                                           int E, int NBUCK) {
    __shared__ int cnt[1024];
    __shared__ int lbase[1024];
    int t = threadIdx.x;
    for (int i = t; i < NBUCK; i += 256) cnt[i] = 0;
    __syncthreads();
    int e0 = blockIdx.x * BINA_CHUNK;
    int e1 = min(e0 + BINA_CHUNK, E);
    for (int e = e0 + t; e < e1; e += 256)
        atomicAdd(&cnt[dst[e] >> BW_SHIFT], 1);
    __syncthreads();
    for (int i = t; i < NBUCK; i += 256) {
        int c = cnt[i];
        lbase[i] = c ? atomicAdd(&gcursor[i], c) : 0;
        cnt[i] = 0;               // reuse as local cursor
    }
    __syncthreads();
    for (int e = e0 + t; e < e1; e += 256) {
        int d = dst[e];
        int bk = d >> BW_SHIFT;
        int p = lbase[bk] + atomicAdd(&cnt[bk], 1);
        binned[p] = (((uint32)(d & (BW_NODES - 1))) << 23) | (uint32)src[e];
    }
}

// ============ Phase B: stage bucket in LDS; deg/dinv/rows; csr written IN PLACE ============
__global__ __launch_bounds__(256) void phaseB_kernel(uint32* __restrict__ binned,
                                                     const int* __restrict__ gcur_end,
                                                     int* __restrict__ rows,
                                                     float* __restrict__ dinv,
                                                     int N) {
    __shared__ uint32 sedge[BUCKET_CAP];          // 36 KB
    __shared__ int deg[BW_NODES];
    __shared__ int sa[BW_NODES], sb[BW_NODES];
    __shared__ int cur[BW_NODES];
    int b = blockIdx.x;
    int node0 = b << BW_SHIFT;
    int nn = min(BW_NODES, N - node0);
    int base = b * BUCKET_CAP;
    int cnt = gcur_end[b] - base;
    int t = threadIdx.x;
    deg[t] = 0; deg[t + 256] = 0;
    __syncthreads();
    for (int e = t; e < cnt; e += 256) {
        uint32 v = binned[base + e];
        sedge[e] = v;
        atomicAdd(&deg[v >> 23], 1);
    }
    __syncthreads();
    for (int i = t; i < nn; i += 256)
        dinv[node0 + i] = rsqrtf(1.0f + (float)deg[i]);
    sa[t] = deg[t]; sa[t + 256] = deg[t + 256];
    __syncthreads();
    int* pa = sa; int* pb = sb;
    for (int off = 1; off < BW_NODES; off <<= 1) {
        for (int i = t; i < BW_NODES; i += 256)
            pb[i] = pa[i] + ((i >= off) ? pa[i - off] : 0);
        __syncthreads();
        int* tmp = pa; pa = pb; pb = tmp;
    }
    for (int i = t; i < BW_NODES; i += 256)
        cur[i] = (i ? pa[i - 1] : 0);
    __syncthreads();
    int* rb = rows + b * 513;
    for (int i = t; i < nn; i += 256)
        rb[i] = base + cur[i];
    if (t == 0) rb[nn] = base + cnt;
    __syncthreads();
    for (int e = t; e < cnt; e += 256) {
        uint32 v = sedge[e];
        int doff = v >> 23;
        int p = base + atomicAdd(&cur[doff], 1);
        binned[p] = v & 0x7FFFFFu;
    }
}

// ============ GEMM1: 4 threads/node x 16 cols; writes h1t[4][N][16] tiled bf16 ============
__global__ __launch_bounds__(256) void gemm1_tn4(const float* __restrict__ x,
                                                 const float* __restrict__ W1,
                                                 const float* __restrict__ dinv,
                                                 unsigned short* __restrict__ h1t, int N) {
    __shared__ float sW[D_IN * H_DIM];      // 32 KB
    int t = threadIdx.x;
    for (int i = t; i < D_IN * H_DIM / 4; i += 256)
        reinterpret_cast<float4*>(sW)[i] = reinterpret_cast<const float4*>(W1)[i];
    __syncthreads();

    int n = blockIdx.x * 64 + (t >> 2);
    if (n >= N) return;
    int p  = t & 3;
    int c0 = p * 16;
    const float4* xr = reinterpret_cast<const float4*>(x + (size_t)n * D_IN);

    float acc[16] = {};
    for (int k0 = 0; k0 < D_IN / 4; ++k0) {
        float4 xv = xr[k0];
        #pragma unroll
        for (int kk = 0; kk < 4; ++kk) {
            float xk = (kk == 0) ? xv.x : (kk == 1) ? xv.y : (kk == 2) ? xv.z : xv.w;
            const float* wrow = &sW[(4 * k0 + kk) * H_DIM + c0];
            #pragma unroll
            for (int c = 0; c < 4; ++c) {
                float4 wv = *reinterpret_cast<const float4*>(wrow + 4 * c);
                acc[4 * c + 0] += xk * wv.x;
                acc[4 * c + 1] += xk * wv.y;
                acc[4 * c + 2] += xk * wv.z;
                acc[4 * c + 3] += xk * wv.w;
            }
        }
    }
    float di = dinv[n];
    unsigned short* orow = h1t + ((size_t)p * N + n) * 16;
    #pragma unroll
    for (int c = 0; c < 4; ++c) {
        ushort4 u;
        u.x = f2bf(acc[4 * c + 0] * di);
        u.y = f2bf(acc[4 * c + 1] * di);
        u.z = f2bf(acc[4 * c + 2] * di);
        u.w = f2bf(acc[4 * c + 3] * di);
        *reinterpret_cast<ushort4*>(orow + 4 * c) = u;
    }
}

// ============ agg1 4-pass: per (node,pass) wave; working set 3.2 MB -> L2-resident ============
// 16 edge slots x 4 lanes x 8B = one gather instruction covers 16 edges of a 32B tile row.
__global__ __launch_bounds__(256) void agg1_pass(const int* __restrict__ rows,
                                                 const int* __restrict__ csr,
                                                 const unsigned short* __restrict__ h1t,
                                                 const float* __restrict__ dinv,
                                                 const float* __restrict__ b1,
                                                 float* __restrict__ z, int N, int NB) {
    int bid = blockIdx.x;
    int p = bid / NB;                           // pass 0..3 (dispatch-order separated)
    int node = (bid - p * NB) * 4 + (threadIdx.x >> 6);
    if (node >= N) return;
    int lane = threadIdx.x & 63;
    int e  = lane >> 2;            // edge slot 0..15
    int fo = (lane & 3) * 4;       // short offset within 16-feat tile
    size_t pN = (size_t)p * N;
    int ridx = node + (node >> BW_SHIFT);
    int s0 = __builtin_amdgcn_readfirstlane(rows[ridx]);
    int s1 = __builtin_amdgcn_readfirstlane(rows[ridx + 1]);

    float a0 = 0.f, a1 = 0.f, a2 = 0.f, a3 = 0.f;
    for (int base = s0; base < s1; base += 64) {
        int cnt = min(64, s1 - base);
        int myc = (lane < cnt) ? csr[base + lane] : 0;
        int j = 0;
        for (; j + 16 <= cnt; j += 16) {       // 16 edges per gather instruction
            uint32 sa = (uint32)__shfl(myc, j + e);
            uint2 hv = *reinterpret_cast<const uint2*>(h1t + (pN + sa) * 16 + fo);
            a0 += __uint_as_float(hv.x << 16);
            a1 += __uint_as_float(hv.x & 0xffff0000u);
            a2 += __uint_as_float(hv.y << 16);
            a3 += __uint_as_float(hv.y & 0xffff0000u);
        }
        if (j < cnt) {
            int idx = j + e;
            uint32 sa = (uint32)__shfl(myc, min(idx, cnt - 1));
            if (idx < cnt) {
                uint2 hv = *reinterpret_cast<const uint2*>(h1t + (pN + sa) * 16 + fo);
                a0 += __uint_as_float(hv.x << 16);
                a1 += __uint_as_float(hv.x & 0xffff0000u);
                a2 += __uint_as_float(hv.y << 16);
                a3 += __uint_as_float(hv.y & 0xffff0000u);
            }
        }
    }
    // reduce 16 edge-slot groups
    a0 += __shfl_xor(a0, 4);  a1 += __shfl_xor(a1, 4);  a2 += __shfl_xor(a2, 4);  a3 += __shfl_xor(a3, 4);
    a0 += __shfl_xor(a0, 8);  a1 += __shfl_xor(a1, 8);  a2 += __shfl_xor(a2, 8);  a3 += __shfl_xor(a3, 8);
    a0 += __shfl_xor(a0, 16); a1 += __shfl_xor(a1, 16); a2 += __shfl_xor(a2, 16); a3 += __shfl_xor(a3, 16);
    a0 += __shfl_xor(a0, 32); a1 += __shfl_xor(a1, 32); a2 += __shfl_xor(a2, 32); a3 += __shfl_xor(a3, 32);

    if (e == 0) {
        uint2 sv = *reinterpret_cast<const uint2*>(h1t + (pN + node) * 16 + fo);
        float4 bv = *reinterpret_cast<const float4*>(b1 + p * 16 + fo);
        float di = dinv[node];
        float4 o;
        o.x = fmaxf(0.f, di * (a0 + __uint_as_float(sv.x << 16)) + bv.x);
        o.y = fmaxf(0.f, di * (a1 + __uint_as_float(sv.x & 0xffff0000u)) + bv.y);
        o.z = fmaxf(0.f, di * (a2 + __uint_as_float(sv.y << 16)) + bv.z);
        o.w = fmaxf(0.f, di * (a3 + __uint_as_float(sv.y & 0xffff0000u)) + bv.w);
        *reinterpret_cast<float4*>(z + (size_t)node * H_DIM + p * 16 + fo) = o;
    }
}

// ============ GEMM2: 2 threads/node x 20 cols; writes h2t[2][N][20] tiled bf16 ============
__global__ __launch_bounds__(256) void gemm2_tn2(const float* __restrict__ z,
                                                 const float* __restrict__ W2,
                                                 const float* __restrict__ dinv,
                                                 unsigned short* __restrict__ h2t, int N) {
    __shared__ float sW[H_DIM * D_OUT];     // 10 KB
    int t = threadIdx.x;
    for (int i = t; i < H_DIM * D_OUT / 4; i += 256)
        reinterpret_cast<float4*>(sW)[i] = reinterpret_cast<const float4*>(W2)[i];
    __syncthreads();

    int n = blockIdx.x * 128 + (t >> 1);
    if (n >= N) return;
    int q  = t & 1;
    int c0 = q * 20;
    const float4* zr = reinterpret_cast<const float4*>(z + (size_t)n * H_DIM);

    float acc[20] = {};
    for (int k0 = 0; k0 < H_DIM / 4; ++k0) {
        float4 zv = zr[k0];
        #pragma unroll
        for (int kk = 0; kk < 4; ++kk) {
            float zk = (kk == 0) ? zv.x : (kk == 1) ? zv.y : (kk == 2) ? zv.z : zv.w;
            const float* wrow = &sW[(4 * k0 + kk) * D_OUT + c0];
            #pragma unroll
            for (int c = 0; c < 5; ++c) {
                float4 wv = *reinterpret_cast<const float4*>(wrow + 4 * c);
                acc[4 * c + 0] += zk * wv.x;
                acc[4 * c + 1] += zk * wv.y;
                acc[4 * c + 2] += zk * wv.z;
                acc[4 * c + 3] += zk * wv.w;
            }
        }
    }
    float di = dinv[n];
    unsigned short* orow = h2t + ((size_t)q * N + n) * 20;
    #pragma unroll
    for (int c = 0; c < 5; ++c) {
        ushort4 u;
        u.x = f2bf(acc[4 * c + 0] * di);
        u.y = f2bf(acc[4 * c + 1] * di);
        u.z = f2bf(acc[4 * c + 2] * di);
        u.w = f2bf(acc[4 * c + 3] * di);
        *reinterpret_cast<ushort4*>(orow + 4 * c) = u;
    }
}

// ============ agg2 2-pass: per (node,pass) wave; 4 MB working set; writes pre-softmax logits ============
// 12 edge slots x 5 lanes x 8B = 12 edges per gather instruction over 40B tile rows.
__global__ __launch_bounds__(256) void agg2_pass(const int* __restrict__ rows,
                                                 const int* __restrict__ csr,
                                                 const unsigned short* __restrict__ h2t,
                                                 const float* __restrict__ dinv,
                                                 const float* __restrict__ b2,
                                                 float* __restrict__ out, int N, int NB) {
    int bid = blockIdx.x;
    int q = bid / NB;                           // pass 0..1
    int node = (bid - q * NB) * 4 + (threadIdx.x >> 6);
    if (node >= N) return;
    int lane = threadIdx.x & 63;
    int g  = lane / 5;             // edge slot 0..11 (12 = idle lanes 60..63)
    int fo = (lane - g * 5) * 4;   // short offset 0..16 within 20-feat tile
    bool gact = g < 12;
    size_t qN = (size_t)q * N;
    int ridx = node + (node >> BW_SHIFT);
    int s0 = __builtin_amdgcn_readfirstlane(rows[ridx]);
    int s1 = __builtin_amdgcn_readfirstlane(rows[ridx + 1]);

    float a0 = 0.f, a1 = 0.f, a2 = 0.f, a3 = 0.f;
    for (int base = s0; base < s1; base += 64) {
        int cnt = min(64, s1 - base);
        int myc = (lane < cnt) ? csr[base + lane] : 0;
        int j = 0;
        for (; j + 12 <= cnt; j += 12) {
            uint32 sa = (uint32)__shfl(myc, min(j + g, cnt - 1));
            if (gact) {
                uint2 hv = *reinterpret_cast<const uint2*>(h2t + (qN + sa) * 20 + fo);
                a0 += __uint_as_float(hv.x << 16);
                a1 += __uint_as_float(hv.x & 0xffff0000u);
                a2 += __uint_as_float(hv.y << 16);
                a3 += __uint_as_float(hv.y & 0xffff0000u);
            }
        }
        if (j < cnt) {
            int idx = j + g;
            uint32 sa = (uint32)__shfl(myc, min(idx, cnt - 1));
            if (gact && idx < cnt) {
                uint2 hv = *reinterpret_cast<const uint2*>(h2t + (qN + sa) * 20 + fo);
                a0 += __uint_as_float(hv.x << 16);
                a1 += __uint_as_float(hv.x & 0xffff0000u);
                a2 += __uint_as_float(hv.y << 16);
                a3 += __uint_as_float(hv.y & 0xffff0000u);
            }
        }
    }
    // reduce 12 groups of 5: +30 (g+=g+6), +15 (g+=g+3), +5/+10 (g0+=g1+g2)
    a0 += __shfl(a0, min(lane + 30, 63)); a1 += __shfl(a1, min(lane + 30, 63));
    a2 += __shfl(a2, min(lane + 30, 63)); a3 += __shfl(a3, min(lane + 30, 63));
    a0 += __shfl(a0, min(lane + 15, 63)); a1 += __shfl(a1, min(lane + 15, 63));
    a2 += __shfl(a2, min(lane + 15, 63)); a3 += __shfl(a3, min(lane + 15, 63));
    a0 += __shfl(a0, min(lane + 5, 63)) + __shfl(a0, min(lane + 10, 63));
    a1 += __shfl(a1, min(lane + 5, 63)) + __shfl(a1, min(lane + 10, 63));
    a2 += __shfl(a2, min(lane + 5, 63)) + __shfl(a2, min(lane + 10, 63));
    a3 += __shfl(a3, min(lane + 5, 63)) + __shfl(a3, min(lane + 10, 63));

    if (lane < 5) {
        uint2 sv = *reinterpret_cast<const uint2*>(h2t + (qN + node) * 20 + fo);
        float4 bv = *reinterpret_cast<const float4*>(b2 + q * 20 + fo);
        float di = dinv[node];
        float4 o;
        o.x = di * (a0 + __uint_as_float(sv.x << 16)) + bv.x;
        o.y = di * (a1 + __uint_as_float(sv.x & 0xffff0000u)) + bv.y;
        o.z = di * (a2 + __uint_as_float(sv.y << 16)) + bv.z;
        o.w = di * (a3 + __uint_as_float(sv.y & 0xffff0000u)) + bv.w;
        *reinterpret_cast<float4*>(out + (size_t)node * D_OUT + q * 20 + fo) = o;
    }
}

// ============ final: in-place log_softmax over 40 logits (wave per node) ============
__global__ __launch_bounds__(256) void softmax_kernel(float* __restrict__ out, int N) {
    int node = blockIdx.x * 4 + (threadIdx.x >> 6);
    if (node >= N) return;
    int lane = threadIdx.x & 63;
    float v = (lane < D_OUT) ? out[(size_t)node * D_OUT + lane] : -INFINITY;
    float m = v;
    for (int off = 32; off > 0; off >>= 1) m = fmaxf(m, __shfl_xor(m, off));
    float ex = (lane < D_OUT) ? __expf(v - m) : 0.f;
    float s = ex;
    for (int off = 32; off > 0; off >>= 1) s += __shfl_xor(s, off);
    float lse = __logf(s);
    if (lane < D_OUT)
        out[(size_t)node * D_OUT + lane] = v - m - lse;
}

extern "C" void kernel_launch(void* const* d_in, const int* in_sizes, int n_in,
                              void* d_out, int out_size, void* d_ws, size_t ws_size,
                              hipStream_t stream) {
    const float* x  = (const float*)d_in[0];
    const int*   ei = (const int*)d_in[1];
    const float* W1 = (const float*)d_in[2];
    const float* b1 = (const float*)d_in[3];
    const float* W2 = (const float*)d_in[4];
    const float* b2 = (const float*)d_in[5];
    float* out = (float*)d_out;

    int N = in_sizes[0] / D_IN;
    int E = in_sizes[1] / 2;
    const int* src = ei;
    const int* dst = ei + E;
    int NBUCK = (N + BW_NODES - 1) / BW_NODES;   // 196 for N=100K (<=1024)

    // ---- workspace layout (~54.5 MB) ----
    char* p = (char*)d_ws;
    int*   gcursor = (int*)p;  p += 4096;
    int*   rows    = (int*)p;  p += ((size_t)NBUCK * 513 + 64) * 4;
    float* dinv    = (float*)p; p += (((size_t)N + 63) & ~(size_t)63) * 4;
    uint32* binned = (uint32*)p; p += (size_t)NBUCK * BUCKET_CAP * 4;   // becomes csr in-place
    unsigned short* h1t = (unsigned short*)p; p += (size_t)N * H_DIM * 2;   // [4][N][16]
    unsigned short* h2t = (unsigned short*)p; p += (((size_t)N * D_OUT * 2 + 255) & ~(size_t)255); // [2][N][20]
    float* z       = (float*)p; p += (size_t)N * H_DIM * 4;

    int binA_blocks = (E + BINA_CHUNK - 1) / BINA_CHUNK;
    int NB = (N + 3) / 4;

    // ---- CSR build: fixed-capacity buckets ----
    cursor_init_kernel<<<(NBUCK + 255) / 256, 256, 0, stream>>>(gcursor, NBUCK);
    binA_scatter_kernel<<<binA_blocks, 256, 0, stream>>>(src, dst, gcursor, binned, E, NBUCK);
    phaseB_kernel<<<NBUCK, 256, 0, stream>>>(binned, gcursor, rows, dinv, N);
    int* csr = (int*)binned;

    // ---- layer 1 ----
    gemm1_tn4<<<(N + 63) / 64, 256, 0, stream>>>(x, W1, dinv, h1t, N);
    agg1_pass<<<4 * NB, 256, 0, stream>>>(rows, csr, h1t, dinv, b1, z, N, NB);

    // ---- layer 2 ----
    gemm2_tn2<<<(N + 127) / 128, 256, 0, stream>>>(z, W2, dinv, h2t, N);
    agg2_pass<<<2 * NB, 256, 0, stream>>>(rows, csr, h2t, dinv, b2, out, N, NB);
    softmax_kernel<<<NB, 256, 0, stream>>>(out, N);
}